// Round 6
// baseline (414.183 us; speedup 1.0000x reference)
//
#include <hip/hip_runtime.h>
#include <hip/hip_bf16.h>

namespace {

typedef __attribute__((ext_vector_type(8))) short short8;   // 8 bf16 = 4 VGPR
typedef __attribute__((ext_vector_type(4))) float f32x4;

constexpr float SSIM_C1 = 0.01f * 0.01f;
constexpr float SSIM_C2 = 0.03f * 0.03f;

// gaussian(sigma=1.5, ws=11)
__device__ __constant__ float GWc[11] = {
    0.00102838f, 0.00759876f, 0.03600077f, 0.10936069f, 0.21300553f,
    0.26601172f, 0.21300553f, 0.10936069f, 0.03600077f, 0.00759876f,
    0.00102838f};

__device__ __forceinline__ unsigned short f2b(float f) {
    return __builtin_bit_cast(unsigned short, __float2bfloat16(f));
}

// 1D blur of the zero-padded all-ones signal at index g (size n), exact f32.
__device__ __forceinline__ float pedge(int g, int n) {
    float s = 0.f;
    #pragma unroll
    for (int k = 0; k < 11; ++k) {
        int t = g + k - 5;
        s += ((unsigned)t < (unsigned)n) ? GWc[k] : 0.f;
    }
    return s;
}

__global__ void init_out(float* out) { out[0] = 1.0f; }

// Tile: 32x32 outputs. q planes hold CENTERED data (x-1/2 etc, zero-padded):
// rows idx 0..43 <-> abs by-5..by+38 (42,43 zeroed), cols idx 0..51 <-> abs
// bx-8..bx+43. h_t planes: [col 0..31][row-slot 0..47], slot s <-> h row idx s;
// slots 44..47 zeroed.
template <bool POOL>
__global__ __launch_bounds__(256, 3)
void ssim_kernel(const float* __restrict__ X, const float* __restrict__ Y,
                 float* __restrict__ out, float coef,
                 float* __restrict__ PX, float* __restrict__ PY,
                 int H, int W)
{
    __shared__ __align__(16) unsigned short q_lds[5][44][56];
    __shared__ __align__(16) unsigned short h_t[5][32][56];
    __shared__ float red[4];

    const int tid = threadIdx.x;
    const int lane = tid & 63;
    const int wid = tid >> 6;
    const int nn = lane & 15;            // MFMA: A-row / B-col / D-col
    const int kb = (lane >> 4) * 8;      // MFMA: k base (8 contiguous k per lane)
    const int n  = blockIdx.z;
    const int by = blockIdx.y * 32;
    const int bx = blockIdx.x * 32;
    const size_t plane = (size_t)H * W;
    const float* Xn = X + (size_t)n * plane;
    const float* Yn = Y + (size_t)n * plane;

    // ---- band fragments (once): Wband[k][c] = GW[k-c] (V); H uses shift-3 ----
    short8 hband, vband;
    #pragma unroll
    for (int e = 0; e < 8; ++e) {
        int d = kb + e - nn;
        float hv = (d >= 3 && d <= 13) ? GWc[d - 3] : 0.f;
        float vv = (d >= 0 && d <= 10) ? GWc[d] : 0.f;
        hband[e] = (short)f2b(hv);
        vband[e] = (short)f2b(vv);
    }

    // ---- fused 2x2 avg-pool for next scale (independent, exact f32) ----
    if (POOL) {
        int pr = tid >> 4, pc = tid & 15;
        int gr = by + 2 * pr, gc = bx + 2 * pc;
        const float* x0 = Xn + (size_t)gr * W + gc;
        const float* y0 = Yn + (size_t)gr * W + gc;
        float2 xa = *(const float2*)x0, xb = *(const float2*)(x0 + W);
        float2 ya = *(const float2*)y0, yb = *(const float2*)(y0 + W);
        int Wp = W >> 1;
        size_t po = (size_t)n * (size_t)(H >> 1) * Wp
                  + (size_t)((by >> 1) + pr) * Wp + ((bx >> 1) + pc);
        PX[po] = 0.25f * (xa.x + xa.y + xb.x + xb.y);
        PY[po] = 0.25f * (ya.x + ya.y + yb.x + yb.y);
    }

    // ---- zero h_t slots 44..47 (read by V k-window with zero weights) ----
    if (tid < 160) {
        int q = tid / 32, c = tid & 31;
        *(ushort4*)&h_t[q][c][44] = make_ushort4(0, 0, 0, 0);
    }

    // ---- phase 1: stage centered cx, cy, cxx, cyy, cxy as bf16 ----
    for (int idx = tid; idx < 44 * 13; idx += 256) {
        int r = idx / 13, g = idx - r * 13;
        int gr = by + r - 5;
        float rm = (r < 42 && (unsigned)gr < (unsigned)H) ? 1.f : 0.f;
        int grc = min(max(gr, 0), H - 1);
        int gc = bx + 4 * g - 8;                  // 4-aligned; W%4==0
        float cm = ((unsigned)gc < (unsigned)W) ? rm : 0.f;
        int gcc = min(max(gc, 0), W - 4);
        const float* xp = Xn + (size_t)grc * W + gcc;
        const float* yp = Yn + (size_t)grc * W + gcc;
        float4 xv = *(const float4*)xp;
        float4 yv = *(const float4*)yp;
        float xa0 = (xv.x - 0.5f) * cm, xa1 = (xv.y - 0.5f) * cm;
        float xa2 = (xv.z - 0.5f) * cm, xa3 = (xv.w - 0.5f) * cm;
        float ya0 = (yv.x - 0.5f) * cm, ya1 = (yv.y - 0.5f) * cm;
        float ya2 = (yv.z - 0.5f) * cm, ya3 = (yv.w - 0.5f) * cm;
        *(ushort4*)&q_lds[0][r][4 * g] =
            make_ushort4(f2b(xa0), f2b(xa1), f2b(xa2), f2b(xa3));
        *(ushort4*)&q_lds[1][r][4 * g] =
            make_ushort4(f2b(ya0), f2b(ya1), f2b(ya2), f2b(ya3));
        *(ushort4*)&q_lds[2][r][4 * g] =
            make_ushort4(f2b(xa0 * xa0), f2b(xa1 * xa1), f2b(xa2 * xa2), f2b(xa3 * xa3));
        *(ushort4*)&q_lds[3][r][4 * g] =
            make_ushort4(f2b(ya0 * ya0), f2b(ya1 * ya1), f2b(ya2 * ya2), f2b(ya3 * ya3));
        *(ushort4*)&q_lds[4][r][4 * g] =
            make_ushort4(f2b(xa0 * ya0), f2b(xa1 * ya1), f2b(xa2 * ya2), f2b(xa3 * ya3));
    }
    __syncthreads();

    // ---- phase 2: H-blur via MFMA. 6 subtiles x 5 quantities = 30 jobs ----
    for (int j = wid; j < 30; j += 4) {
        int st = j / 5, q = j - 5 * st;
        int rg2 = st >> 1;
        int rowg = (rg2 == 0) ? 0 : ((rg2 == 1) ? 16 : 28);
        int c0 = (st & 1) << 4;
        short8 a = *(const short8*)&q_lds[q][rowg + nn][c0 + kb];
        f32x4 d = __builtin_amdgcn_mfma_f32_16x16x32_bf16(
            a, hband, (f32x4){0.f, 0.f, 0.f, 0.f}, 0, 0, 0);
        // D: col = lane&15, rows = rowg + 4*(lane>>4) + {0..3} -> transposed b64 write
        *(ushort4*)&h_t[q][c0 + nn][rowg + ((lane >> 4) << 2)] =
            make_ushort4(f2b(d[0]), f2b(d[1]), f2b(d[2]), f2b(d[3]));
    }
    __syncthreads();

    // ---- phase 3: V-blur via MFMA + SSIM epilogue. One 16x16 subtile/wave ----
    const int r0 = (wid >> 1) << 4;
    const int c0 = (wid & 1) << 4;
    f32x4 dq[5];
    #pragma unroll
    for (int q = 0; q < 5; ++q) {
        short8 b = *(const short8*)&h_t[q][c0 + nn][r0 + kb];
        dq[q] = __builtin_amdgcn_mfma_f32_16x16x32_bf16(
            vband, b, (f32x4){0.f, 0.f, 0.f, 0.f}, 0, 0, 0);
    }

    // output pixel: local row = r0 + 4*(lane>>4) + ri, local col = c0 + nn
    const int gr0 = by + r0 + ((lane >> 4) << 2);
    const int gc  = bx + c0 + nn;
    const float Ph = pedge(gc, W);

    float acc = 0.f;
    #pragma unroll
    for (int ri = 0; ri < 4; ++ri) {
        float P   = pedge(gr0 + ri, H) * Ph;   // blur of padded ones, exact
        float omP = 1.f - P;
        float tP  = 0.25f * P * omP;
        float m1 = dq[0][ri], m2 = dq[1][ri];          // centered means
        float sxx = dq[2][ri], syy = dq[3][ri], sxy = dq[4][ri];
        float mu1 = m1 + 0.5f * P, mu2 = m2 + 0.5f * P;
        float s1  = sxx - m1 * m1 + omP * m1 + tP;
        float s2  = syy - m2 * m2 + omP * m2 + tP;
        float s12 = sxy - m1 * m2 + 0.5f * omP * (m1 + m2) + tP;
        float mu1s = mu1 * mu1, mu2s = mu2 * mu2, mu12 = mu1 * mu2;
        float num = (2.f * mu12 + SSIM_C1) * (2.f * s12 + SSIM_C2);
        float den = (mu1s + mu2s + SSIM_C1) * (s1 + s2 + SSIM_C2);
        acc += num / den;
    }

    // ---- block reduction ----
    #pragma unroll
    for (int off = 32; off > 0; off >>= 1)
        acc += __shfl_down(acc, off, 64);
    if ((tid & 63) == 0) red[wid] = acc;
    __syncthreads();
    if (tid == 0) {
        float s = red[0] + red[1] + red[2] + red[3];
        atomicAdd(out, -coef * s);
    }
}

} // namespace

extern "C" void kernel_launch(void* const* d_in, const int* in_sizes, int n_in,
                              void* d_out, int out_size, void* d_ws, size_t ws_size,
                              hipStream_t stream)
{
    const float* pred = (const float*)d_in[0];
    const float* targ = (const float*)d_in[1];
    float* out = (float*)d_out;

    const int N = 64;
    float* p1 = (float*)d_ws;                        // 64*256*256 fp32
    float* t1 = p1 + (size_t)N * 256 * 256;
    float* p2 = t1 + (size_t)N * 256 * 256;          // 64*128*128 fp32
    float* t2 = p2 + (size_t)N * 128 * 128;

    hipLaunchKernelGGL(init_out, dim3(1), dim3(1), 0, stream, out);

    const dim3 blk(256);
    hipLaunchKernelGGL((ssim_kernel<true>), dim3(16, 16, N), blk, 0, stream,
                       pred, targ, out, 0.5f / (N * 512.f * 512.f), p1, t1, 512, 512);
    hipLaunchKernelGGL((ssim_kernel<true>), dim3(8, 8, N), blk, 0, stream,
                       p1, t1, out, 0.3f / (N * 256.f * 256.f), p2, t2, 256, 256);
    hipLaunchKernelGGL((ssim_kernel<false>), dim3(4, 4, N), blk, 0, stream,
                       p2, t2, out, 0.2f / (N * 128.f * 128.f), nullptr, nullptr, 128, 128);
}

// Round 7
// 404.867 us; speedup vs baseline: 1.0230x; 1.0230x over previous
//
#include <hip/hip_runtime.h>
#include <hip/hip_bf16.h>

namespace {

typedef __attribute__((ext_vector_type(8))) short short8;   // 8 bf16 = 4 VGPR
typedef __attribute__((ext_vector_type(4))) float f32x4;

constexpr float SSIM_C1 = 0.01f * 0.01f;
constexpr float SSIM_C2 = 0.03f * 0.03f;

// gaussian(sigma=1.5, ws=11)
__device__ __constant__ float GWc[11] = {
    0.00102838f, 0.00759876f, 0.03600077f, 0.10936069f, 0.21300553f,
    0.26601172f, 0.21300553f, 0.10936069f, 0.03600077f, 0.00759876f,
    0.00102838f};

__device__ __forceinline__ unsigned short f2b(float f) {
    return __builtin_bit_cast(unsigned short, __float2bfloat16(f));
}

// 1D blur of zero-padded ones at index g (size n). Fast path: window fully
// inside -> 1.0 (wave-uniform branch except in border tiles).
__device__ __forceinline__ float pedge(int g, int n) {
    if (g >= 5 && g + 6 <= n) return 1.f;
    float s = 0.f;
    #pragma unroll
    for (int k = 0; k < 11; ++k) {
        int t = g + k - 5;
        s += ((unsigned)t < (unsigned)n) ? GWc[k] : 0.f;
    }
    return s;
}

__global__ void init_out(float* out) { out[0] = 1.0f; }

// Tile: 32x32 outputs. Centered data (x-1/2, zero-padded outside image).
// Tile col idx c (0..51) <-> abs col bx+c-8; row idx r (0..43) <-> abs by+r-5,
// rows 42,43 forced zero. h_t: [quantity][col 0..31][row-slot 0..47] bf16,
// slots 44..47 zeroed. Fragment layouts identical to the verified r6 kernel.
template <bool POOL>
__global__ __launch_bounds__(256, 5)
void ssim_kernel(const float* __restrict__ X, const float* __restrict__ Y,
                 float* __restrict__ out, float coef,
                 float* __restrict__ PX, float* __restrict__ PY,
                 int H, int W)
{
    __shared__ __align__(16) unsigned short h_t[5][32][56];
    __shared__ float red[4];

    const int tid = threadIdx.x;
    const int lane = tid & 63;
    const int wid = tid >> 6;
    const int nn = lane & 15;            // MFMA: A-row / B-col / D-col
    const int kb = (lane >> 4) * 8;      // MFMA: k base (8 contiguous k)
    const int n  = blockIdx.z;
    const int by = blockIdx.y * 32;
    const int bx = blockIdx.x * 32;
    const size_t plane = (size_t)H * W;
    const float* Xn = X + (size_t)n * plane;
    const float* Yn = Y + (size_t)n * plane;

    // ---- band fragments: Wband[k][c] = GW[k-c] (V); H uses shift-3 ----
    short8 hband, vband;
    #pragma unroll
    for (int e = 0; e < 8; ++e) {
        int d = kb + e - nn;
        float hv = (d >= 3 && d <= 13) ? GWc[d - 3] : 0.f;
        float vv = (d >= 0 && d <= 10) ? GWc[d] : 0.f;
        hband[e] = (short)f2b(hv);
        vband[e] = (short)f2b(vv);
    }

    // ---- fused 2x2 avg-pool for next scale (independent, exact f32) ----
    if (POOL) {
        int pr = tid >> 4, pc = tid & 15;
        int gr = by + 2 * pr, gc = bx + 2 * pc;
        const float* x0 = Xn + (size_t)gr * W + gc;
        const float* y0 = Yn + (size_t)gr * W + gc;
        float2 xa = *(const float2*)x0, xb = *(const float2*)(x0 + W);
        float2 ya = *(const float2*)y0, yb = *(const float2*)(y0 + W);
        int Wp = W >> 1;
        size_t po = (size_t)n * (size_t)(H >> 1) * Wp
                  + (size_t)((by >> 1) + pr) * Wp + ((bx >> 1) + pc);
        PX[po] = 0.25f * (xa.x + xa.y + xb.x + xb.y);
        PY[po] = 0.25f * (ya.x + ya.y + yb.x + yb.y);
    }

    // ---- zero h_t slots 44..47 (read by V k-window with zero weights) ----
    if (tid < 160) {
        int q = tid / 32, c = tid & 31;
        *(ushort4*)&h_t[q][c][44] = make_ushort4(0, 0, 0, 0);
    }

    // ---- phase H: per-lane global loads -> 5 fragments -> MFMA -> h_t ----
    // 6 subtiles: rowg in {0,16,28} x c0 in {0,16}; waves 0,1 take two.
    auto hjob = [&](int st) {
        int rg2 = st >> 1;
        int rowg = (rg2 == 0) ? 0 : ((rg2 == 1) ? 16 : 28);
        int c0s = (st & 1) << 4;
        int ridx = rowg + nn;              // tile row idx 0..43
        int gr = by + ridx - 5;
        bool rok = (ridx < 42) && ((unsigned)gr < (unsigned)H);
        int grc = min(max(gr, 0), H - 1);
        const float* xrow = Xn + (size_t)grc * W;
        const float* yrow = Yn + (size_t)grc * W;
        int cb = bx + c0s + kb - 8;        // 4-aligned; W%4==0
        float ma = (rok && (unsigned)cb < (unsigned)W) ? 1.f : 0.f;
        float mb = (rok && (unsigned)(cb + 4) < (unsigned)W) ? 1.f : 0.f;
        int ca  = min(max(cb, 0), W - 4);
        int cb2 = min(max(cb + 4, 0), W - 4);
        float4 xa = *(const float4*)(xrow + ca);
        float4 xb = *(const float4*)(xrow + cb2);
        float4 ya = *(const float4*)(yrow + ca);
        float4 yb = *(const float4*)(yrow + cb2);
        float cx[8] = {(xa.x - 0.5f) * ma, (xa.y - 0.5f) * ma,
                       (xa.z - 0.5f) * ma, (xa.w - 0.5f) * ma,
                       (xb.x - 0.5f) * mb, (xb.y - 0.5f) * mb,
                       (xb.z - 0.5f) * mb, (xb.w - 0.5f) * mb};
        float cy[8] = {(ya.x - 0.5f) * ma, (ya.y - 0.5f) * ma,
                       (ya.z - 0.5f) * ma, (ya.w - 0.5f) * ma,
                       (yb.x - 0.5f) * mb, (yb.y - 0.5f) * mb,
                       (yb.z - 0.5f) * mb, (yb.w - 0.5f) * mb};
        short8 fx, fy, fxx, fyy, fxy;
        #pragma unroll
        for (int e = 0; e < 8; ++e) {
            fx[e]  = (short)f2b(cx[e]);
            fy[e]  = (short)f2b(cy[e]);
            fxx[e] = (short)f2b(cx[e] * cx[e]);
            fyy[e] = (short)f2b(cy[e] * cy[e]);
            fxy[e] = (short)f2b(cx[e] * cy[e]);
        }
        f32x4 z = {0.f, 0.f, 0.f, 0.f};
        f32x4 d0 = __builtin_amdgcn_mfma_f32_16x16x32_bf16(fx,  hband, z, 0, 0, 0);
        f32x4 d1 = __builtin_amdgcn_mfma_f32_16x16x32_bf16(fy,  hband, z, 0, 0, 0);
        f32x4 d2 = __builtin_amdgcn_mfma_f32_16x16x32_bf16(fxx, hband, z, 0, 0, 0);
        f32x4 d3 = __builtin_amdgcn_mfma_f32_16x16x32_bf16(fyy, hband, z, 0, 0, 0);
        f32x4 d4 = __builtin_amdgcn_mfma_f32_16x16x32_bf16(fxy, hband, z, 0, 0, 0);
        // D: col = lane&15 -> h col c0s+nn; rows rowg+4*(lane>>4)+{0..3}
        int ws_ = rowg + ((lane >> 4) << 2);
        int cc  = c0s + nn;
        *(ushort4*)&h_t[0][cc][ws_] = make_ushort4(f2b(d0[0]), f2b(d0[1]), f2b(d0[2]), f2b(d0[3]));
        *(ushort4*)&h_t[1][cc][ws_] = make_ushort4(f2b(d1[0]), f2b(d1[1]), f2b(d1[2]), f2b(d1[3]));
        *(ushort4*)&h_t[2][cc][ws_] = make_ushort4(f2b(d2[0]), f2b(d2[1]), f2b(d2[2]), f2b(d2[3]));
        *(ushort4*)&h_t[3][cc][ws_] = make_ushort4(f2b(d3[0]), f2b(d3[1]), f2b(d3[2]), f2b(d3[3]));
        *(ushort4*)&h_t[4][cc][ws_] = make_ushort4(f2b(d4[0]), f2b(d4[1]), f2b(d4[2]), f2b(d4[3]));
    };
    hjob(wid);
    if (wid < 2) hjob(wid + 4);
    __syncthreads();

    // ---- phase V: MFMA + SSIM epilogue. One 16x16 subtile per wave ----
    const int r0 = (wid >> 1) << 4;
    const int c0 = (wid & 1) << 4;
    f32x4 dq[5];
    #pragma unroll
    for (int q = 0; q < 5; ++q) {
        short8 b = *(const short8*)&h_t[q][c0 + nn][r0 + kb];
        dq[q] = __builtin_amdgcn_mfma_f32_16x16x32_bf16(
            vband, b, (f32x4){0.f, 0.f, 0.f, 0.f}, 0, 0, 0);
    }

    const int gr0 = by + r0 + ((lane >> 4) << 2);
    const int gc  = bx + c0 + nn;
    const float Ph = pedge(gc, W);

    float acc = 0.f;
    #pragma unroll
    for (int ri = 0; ri < 4; ++ri) {
        float P   = pedge(gr0 + ri, H) * Ph;   // blur of padded ones, exact
        float omP = 1.f - P;
        float tP  = 0.25f * P * omP;
        float m1 = dq[0][ri], m2 = dq[1][ri];          // centered means
        float sxx = dq[2][ri], syy = dq[3][ri], sxy = dq[4][ri];
        float mu1 = m1 + 0.5f * P, mu2 = m2 + 0.5f * P;
        float s1  = sxx - m1 * m1 + omP * m1 + tP;
        float s2  = syy - m2 * m2 + omP * m2 + tP;
        float s12 = sxy - m1 * m2 + 0.5f * omP * (m1 + m2) + tP;
        float mu1s = mu1 * mu1, mu2s = mu2 * mu2, mu12 = mu1 * mu2;
        float num = (2.f * mu12 + SSIM_C1) * (2.f * s12 + SSIM_C2);
        float den = (mu1s + mu2s + SSIM_C1) * (s1 + s2 + SSIM_C2);
        acc += num / den;
    }

    // ---- block reduction ----
    #pragma unroll
    for (int off = 32; off > 0; off >>= 1)
        acc += __shfl_down(acc, off, 64);
    if ((tid & 63) == 0) red[wid] = acc;
    __syncthreads();
    if (tid == 0) {
        float s = red[0] + red[1] + red[2] + red[3];
        atomicAdd(out, -coef * s);
    }
}

} // namespace

extern "C" void kernel_launch(void* const* d_in, const int* in_sizes, int n_in,
                              void* d_out, int out_size, void* d_ws, size_t ws_size,
                              hipStream_t stream)
{
    const float* pred = (const float*)d_in[0];
    const float* targ = (const float*)d_in[1];
    float* out = (float*)d_out;

    const int N = 64;
    float* p1 = (float*)d_ws;                        // 64*256*256 fp32
    float* t1 = p1 + (size_t)N * 256 * 256;
    float* p2 = t1 + (size_t)N * 256 * 256;          // 64*128*128 fp32
    float* t2 = p2 + (size_t)N * 128 * 128;

    hipLaunchKernelGGL(init_out, dim3(1), dim3(1), 0, stream, out);

    const dim3 blk(256);
    hipLaunchKernelGGL((ssim_kernel<true>), dim3(16, 16, N), blk, 0, stream,
                       pred, targ, out, 0.5f / (N * 512.f * 512.f), p1, t1, 512, 512);
    hipLaunchKernelGGL((ssim_kernel<true>), dim3(8, 8, N), blk, 0, stream,
                       p1, t1, out, 0.3f / (N * 256.f * 256.f), p2, t2, 256, 256);
    hipLaunchKernelGGL((ssim_kernel<false>), dim3(4, 4, N), blk, 0, stream,
                       p2, t2, out, 0.2f / (N * 128.f * 128.f), nullptr, nullptr, 128, 128);
}

// Round 8
// 267.864 us; speedup vs baseline: 1.5462x; 1.5115x over previous
//
#include <hip/hip_runtime.h>
#include <hip/hip_bf16.h>

namespace {

typedef __attribute__((ext_vector_type(8))) short short8;   // 8 bf16 = 4 VGPR
typedef __attribute__((ext_vector_type(4))) float f32x4;

constexpr float SSIM_C1 = 0.01f * 0.01f;
constexpr float SSIM_C2 = 0.03f * 0.03f;

// gaussian(sigma=1.5, ws=11)
__device__ __constant__ float GWc[11] = {
    0.00102838f, 0.00759876f, 0.03600077f, 0.10936069f, 0.21300553f,
    0.26601172f, 0.21300553f, 0.10936069f, 0.03600077f, 0.00759876f,
    0.00102838f};

__device__ __forceinline__ unsigned short f2b(float f) {
    return __builtin_bit_cast(unsigned short, __float2bfloat16(f));
}

// 1D blur of zero-padded ones at index g (size n). Fast path: window fully
// inside -> 1.0 (wave-uniform branch except in border tiles).
__device__ __forceinline__ float pedge(int g, int n) {
    if (g >= 5 && g + 6 <= n) return 1.f;
    float s = 0.f;
    #pragma unroll
    for (int k = 0; k < 11; ++k) {
        int t = g + k - 5;
        s += ((unsigned)t < (unsigned)n) ? GWc[k] : 0.f;
    }
    return s;
}

// Tile: 32x32 outputs. Centered data (x-1/2, zero-padded outside image).
// Tile col idx c (0..51) <-> abs col bx+c-8; row idx r (0..43) <-> abs by+r-5,
// rows 42,43 forced zero. h_t: [quantity][col 0..31][row-slot 0..47] bf16,
// slots 44..47 zeroed. Fragment layouts identical to the verified r6/r7 kernel.
// NO same-address atomics: each block stores coef*sum(ssim) to its own slot.
template <bool POOL>
__global__ __launch_bounds__(256, 5)
void ssim_kernel(const float* __restrict__ X, const float* __restrict__ Y,
                 float* __restrict__ partials, float coef,
                 float* __restrict__ PX, float* __restrict__ PY,
                 int H, int W)
{
    __shared__ __align__(16) unsigned short h_t[5][32][56];
    __shared__ float red[4];

    const int tid = threadIdx.x;
    const int lane = tid & 63;
    const int wid = tid >> 6;
    const int nn = lane & 15;            // MFMA: A-row / B-col / D-col
    const int kb = (lane >> 4) * 8;      // MFMA: k base (8 contiguous k)
    const int n  = blockIdx.z;
    const int by = blockIdx.y * 32;
    const int bx = blockIdx.x * 32;
    const size_t plane = (size_t)H * W;
    const float* Xn = X + (size_t)n * plane;
    const float* Yn = Y + (size_t)n * plane;

    // ---- band fragments: Wband[k][c] = GW[k-c] (V); H uses shift-3 ----
    short8 hband, vband;
    #pragma unroll
    for (int e = 0; e < 8; ++e) {
        int d = kb + e - nn;
        float hv = (d >= 3 && d <= 13) ? GWc[d - 3] : 0.f;
        float vv = (d >= 0 && d <= 10) ? GWc[d] : 0.f;
        hband[e] = (short)f2b(hv);
        vband[e] = (short)f2b(vv);
    }

    // ---- fused 2x2 avg-pool for next scale (independent, exact f32) ----
    if (POOL) {
        int pr = tid >> 4, pc = tid & 15;
        int gr = by + 2 * pr, gc = bx + 2 * pc;
        const float* x0 = Xn + (size_t)gr * W + gc;
        const float* y0 = Yn + (size_t)gr * W + gc;
        float2 xa = *(const float2*)x0, xb = *(const float2*)(x0 + W);
        float2 ya = *(const float2*)y0, yb = *(const float2*)(y0 + W);
        int Wp = W >> 1;
        size_t po = (size_t)n * (size_t)(H >> 1) * Wp
                  + (size_t)((by >> 1) + pr) * Wp + ((bx >> 1) + pc);
        PX[po] = 0.25f * (xa.x + xa.y + xb.x + xb.y);
        PY[po] = 0.25f * (ya.x + ya.y + yb.x + yb.y);
    }

    // ---- zero h_t slots 44..47 (read by V k-window with zero weights) ----
    if (tid < 160) {
        int q = tid / 32, c = tid & 31;
        *(ushort4*)&h_t[q][c][44] = make_ushort4(0, 0, 0, 0);
    }

    // ---- phase H: per-lane global loads -> 5 fragments -> MFMA -> h_t ----
    // 6 subtiles: rowg in {0,16,28} x c0 in {0,16}; waves 0,1 take two.
    auto hjob = [&](int st) {
        int rg2 = st >> 1;
        int rowg = (rg2 == 0) ? 0 : ((rg2 == 1) ? 16 : 28);
        int c0s = (st & 1) << 4;
        int ridx = rowg + nn;              // tile row idx 0..43
        int gr = by + ridx - 5;
        bool rok = (ridx < 42) && ((unsigned)gr < (unsigned)H);
        int grc = min(max(gr, 0), H - 1);
        const float* xrow = Xn + (size_t)grc * W;
        const float* yrow = Yn + (size_t)grc * W;
        int cb = bx + c0s + kb - 8;        // 4-aligned; W%4==0
        float ma = (rok && (unsigned)cb < (unsigned)W) ? 1.f : 0.f;
        float mb = (rok && (unsigned)(cb + 4) < (unsigned)W) ? 1.f : 0.f;
        int ca  = min(max(cb, 0), W - 4);
        int cb2 = min(max(cb + 4, 0), W - 4);
        float4 xa = *(const float4*)(xrow + ca);
        float4 xb = *(const float4*)(xrow + cb2);
        float4 ya = *(const float4*)(yrow + ca);
        float4 yb = *(const float4*)(yrow + cb2);
        float cx[8] = {(xa.x - 0.5f) * ma, (xa.y - 0.5f) * ma,
                       (xa.z - 0.5f) * ma, (xa.w - 0.5f) * ma,
                       (xb.x - 0.5f) * mb, (xb.y - 0.5f) * mb,
                       (xb.z - 0.5f) * mb, (xb.w - 0.5f) * mb};
        float cy[8] = {(ya.x - 0.5f) * ma, (ya.y - 0.5f) * ma,
                       (ya.z - 0.5f) * ma, (ya.w - 0.5f) * ma,
                       (yb.x - 0.5f) * mb, (yb.y - 0.5f) * mb,
                       (yb.z - 0.5f) * mb, (yb.w - 0.5f) * mb};
        short8 fx, fy, fxx, fyy, fxy;
        #pragma unroll
        for (int e = 0; e < 8; ++e) {
            fx[e]  = (short)f2b(cx[e]);
            fy[e]  = (short)f2b(cy[e]);
            fxx[e] = (short)f2b(cx[e] * cx[e]);
            fyy[e] = (short)f2b(cy[e] * cy[e]);
            fxy[e] = (short)f2b(cx[e] * cy[e]);
        }
        f32x4 z = {0.f, 0.f, 0.f, 0.f};
        f32x4 d0 = __builtin_amdgcn_mfma_f32_16x16x32_bf16(fx,  hband, z, 0, 0, 0);
        f32x4 d1 = __builtin_amdgcn_mfma_f32_16x16x32_bf16(fy,  hband, z, 0, 0, 0);
        f32x4 d2 = __builtin_amdgcn_mfma_f32_16x16x32_bf16(fxx, hband, z, 0, 0, 0);
        f32x4 d3 = __builtin_amdgcn_mfma_f32_16x16x32_bf16(fyy, hband, z, 0, 0, 0);
        f32x4 d4 = __builtin_amdgcn_mfma_f32_16x16x32_bf16(fxy, hband, z, 0, 0, 0);
        // D: col = lane&15 -> h col c0s+nn; rows rowg+4*(lane>>4)+{0..3}
        int ws_ = rowg + ((lane >> 4) << 2);
        int cc  = c0s + nn;
        *(ushort4*)&h_t[0][cc][ws_] = make_ushort4(f2b(d0[0]), f2b(d0[1]), f2b(d0[2]), f2b(d0[3]));
        *(ushort4*)&h_t[1][cc][ws_] = make_ushort4(f2b(d1[0]), f2b(d1[1]), f2b(d1[2]), f2b(d1[3]));
        *(ushort4*)&h_t[2][cc][ws_] = make_ushort4(f2b(d2[0]), f2b(d2[1]), f2b(d2[2]), f2b(d2[3]));
        *(ushort4*)&h_t[3][cc][ws_] = make_ushort4(f2b(d3[0]), f2b(d3[1]), f2b(d3[2]), f2b(d3[3]));
        *(ushort4*)&h_t[4][cc][ws_] = make_ushort4(f2b(d4[0]), f2b(d4[1]), f2b(d4[2]), f2b(d4[3]));
    };
    hjob(wid);
    if (wid < 2) hjob(wid + 4);
    __syncthreads();

    // ---- phase V: MFMA + SSIM epilogue. One 16x16 subtile per wave ----
    const int r0 = (wid >> 1) << 4;
    const int c0 = (wid & 1) << 4;
    f32x4 dq[5];
    #pragma unroll
    for (int q = 0; q < 5; ++q) {
        short8 b = *(const short8*)&h_t[q][c0 + nn][r0 + kb];
        dq[q] = __builtin_amdgcn_mfma_f32_16x16x32_bf16(
            vband, b, (f32x4){0.f, 0.f, 0.f, 0.f}, 0, 0, 0);
    }

    const int gr0 = by + r0 + ((lane >> 4) << 2);
    const int gc  = bx + c0 + nn;
    const float Ph = pedge(gc, W);

    float acc = 0.f;
    #pragma unroll
    for (int ri = 0; ri < 4; ++ri) {
        float P   = pedge(gr0 + ri, H) * Ph;   // blur of padded ones, exact
        float omP = 1.f - P;
        float tP  = 0.25f * P * omP;
        float m1 = dq[0][ri], m2 = dq[1][ri];          // centered means
        float sxx = dq[2][ri], syy = dq[3][ri], sxy = dq[4][ri];
        float mu1 = m1 + 0.5f * P, mu2 = m2 + 0.5f * P;
        float s1  = sxx - m1 * m1 + omP * m1 + tP;
        float s2  = syy - m2 * m2 + omP * m2 + tP;
        float s12 = sxy - m1 * m2 + 0.5f * omP * (m1 + m2) + tP;
        float mu1s = mu1 * mu1, mu2s = mu2 * mu2, mu12 = mu1 * mu2;
        float num = (2.f * mu12 + SSIM_C1) * (2.f * s12 + SSIM_C2);
        float den = (mu1s + mu2s + SSIM_C1) * (s1 + s2 + SSIM_C2);
        acc += num / den;
    }

    // ---- block reduction -> private partial slot (no atomics) ----
    #pragma unroll
    for (int off = 32; off > 0; off >>= 1)
        acc += __shfl_down(acc, off, 64);
    if ((tid & 63) == 0) red[wid] = acc;
    __syncthreads();
    if (tid == 0) {
        float s = red[0] + red[1] + red[2] + red[3];
        int bid = (blockIdx.z * gridDim.y + blockIdx.y) * gridDim.x + blockIdx.x;
        partials[bid] = coef * s;
    }
}

// out[0] = 1 - sum(partials[0..n)) ; single block, no atomics
__global__ __launch_bounds__(1024)
void final_reduce(const float* __restrict__ partials, int n, float* __restrict__ out)
{
    __shared__ float red[16];
    float s = 0.f;
    for (int i = threadIdx.x; i < n; i += 1024) s += partials[i];
    #pragma unroll
    for (int off = 32; off > 0; off >>= 1) s += __shfl_down(s, off, 64);
    if ((threadIdx.x & 63) == 0) red[threadIdx.x >> 6] = s;
    __syncthreads();
    if (threadIdx.x == 0) {
        float t = 0.f;
        #pragma unroll
        for (int i = 0; i < 16; ++i) t += red[i];
        out[0] = 1.0f - t;
    }
}

} // namespace

extern "C" void kernel_launch(void* const* d_in, const int* in_sizes, int n_in,
                              void* d_out, int out_size, void* d_ws, size_t ws_size,
                              hipStream_t stream)
{
    const float* pred = (const float*)d_in[0];
    const float* targ = (const float*)d_in[1];
    float* out = (float*)d_out;

    const int N = 64;
    float* p1 = (float*)d_ws;                        // 64*256*256 fp32
    float* t1 = p1 + (size_t)N * 256 * 256;
    float* p2 = t1 + (size_t)N * 256 * 256;          // 64*128*128 fp32
    float* t2 = p2 + (size_t)N * 128 * 128;
    float* parts = t2 + (size_t)N * 128 * 128;       // 21504 partials
    const int NP0 = 16 * 16 * N;                     // 16384
    const int NP1 = 8 * 8 * N;                       // 4096
    const int NP2 = 4 * 4 * N;                       // 1024
    const int NP  = NP0 + NP1 + NP2;                 // 21504

    const dim3 blk(256);
    hipLaunchKernelGGL((ssim_kernel<true>), dim3(16, 16, N), blk, 0, stream,
                       pred, targ, parts, 0.5f / (N * 512.f * 512.f), p1, t1, 512, 512);
    hipLaunchKernelGGL((ssim_kernel<true>), dim3(8, 8, N), blk, 0, stream,
                       p1, t1, parts + NP0, 0.3f / (N * 256.f * 256.f), p2, t2, 256, 256);
    hipLaunchKernelGGL((ssim_kernel<false>), dim3(4, 4, N), blk, 0, stream,
                       p2, t2, parts + NP0 + NP1, 0.2f / (N * 128.f * 128.f),
                       nullptr, nullptr, 128, 128);
    hipLaunchKernelGGL(final_reduce, dim3(1), dim3(1024), 0, stream, parts, NP, out);
}